// Round 1
// baseline (143.043 us; speedup 1.0000x reference)
//
#include <hip/hip_runtime.h>
#include <math.h>

#define N_VAR 8192
#define N_CHK 4096
#define DC 6
#define N_EDGE 24576          // N_VAR*3 == N_CHK*6
#define BATCH 512
#define N_ITER 5
#define CLIP_F 0.99999988f    // float32(1 - 1e-7)
#define NTHREADS 1024
#define VPT (N_VAR / NTHREADS)   // 8 vars per thread
#define CPT (N_CHK / NTHREADS)   // 4 checks per thread

// ---- workspace layout: [0, N_CHK) int counters | [N_CHK, N_CHK + N_CHK*DC) chk_edges ----

__global__ void k_build(const int* __restrict__ chk_index,
                        int* __restrict__ cnt,
                        int* __restrict__ chk_edges) {
    int e = blockIdx.x * blockDim.x + threadIdx.x;
    if (e < N_EDGE) {
        int c = chk_index[e];
        int p = atomicAdd(&cnt[c], 1);
        // slot order within a check is irrelevant (LOO product is symmetric)
        chk_edges[c * DC + p] = e;
    }
}

// q-domain SPA. R3 theory: LDS pipe (~45% duty incl. random-perm bank conflicts)
// and VALU (~50%) were running nearly SERIALIZED — the barrier-synced
// load-all/compute-all/store-all phases make all 16 waves burst on one pipe at
// a time. This version software-pipelines each phase per-thread (depth-2
// rotating prefetch buffers, all indices compile-time) so scattered LDS reads
// of check/var k+2 are in flight while check/var k computes and stores.
// Scatter addresses are pre-scaled to byte offsets (saves the per-use shl).
__launch_bounds__(1024, 4)   // cap VGPR at 128: keep all 16 waves resident
__global__ void k_spa(const float* __restrict__ llr,
                      const int* __restrict__ chk_edges,
                      float* __restrict__ out) {
    __shared__ float m[N_EDGE];   // 96 KB, 1 block/CU
    const int b = blockIdx.x;
    const int tid = threadIdx.x;
    const float* __restrict__ lrow = llr + (size_t)b * N_VAR;
    float* __restrict__ orow = out + (size_t)b * N_VAR;
    char* mb = (char*)m;          // byte-addressed view for pre-scaled offsets

    // iteration-invariant per-thread state in registers
    float l[VPT], el[VPT];
    #pragma unroll
    for (int k = 0; k < VPT; ++k) {
        int v = tid + k * NTHREADS;
        l[k]  = lrow[v];
        el[k] = __expf(l[k]);     // exp(llr): once per var total
    }
    int ceb[CPT][DC];             // byte offsets of this thread's check edges
    #pragma unroll
    for (int k = 0; k < CPT; ++k) {
        int c = tid + k * NTHREADS;
        #pragma unroll
        for (int j = 0; j < DC; ++j) ceb[k][j] = chk_edges[c * DC + j] << 2;
    }

    // ---- iter-0 variable phase: ext=0 -> msg=llr -> t=(el-1)/(el+1), same on all 3 edges ----
    #pragma unroll
    for (int k = 0; k < VPT; ++k) {
        int v = tid + k * NTHREADS;
        float t0 = (el[k] - 1.0f) * __builtin_amdgcn_rcpf(el[k] + 1.0f);
        m[3 * v] = t0; m[3 * v + 1] = t0; m[3 * v + 2] = t0;
    }
    __syncthreads();

    #pragma unroll 1
    for (int iter = 0; iter < N_ITER; ++iter) {
        // ---- check phase: depth-2 pipelined gather -> compute -> scatter ----
        // In-place is race-free: edges partition by check, each edge touched by
        // exactly one thread in this phase.
        {
            float tb[3][DC];      // rotating prefetch buffers (indices static)
            #pragma unroll
            for (int s = 0; s < CPT + 2; ++s) {
                if (s < CPT) {
                    #pragma unroll
                    for (int j = 0; j < DC; ++j)
                        tb[s % 3][j] = *(const float*)(mb + ceb[s][j]);
                }
                if (s >= 2) {
                    const int k = s - 2;
                    const float* tq = tb[k % 3];
                    float pre[DC + 1], suf[DC + 1];
                    pre[0] = 1.0f; suf[DC] = 1.0f;
                    #pragma unroll
                    for (int j = 0; j < DC; ++j)      pre[j + 1] = pre[j] * tq[j];
                    #pragma unroll
                    for (int j = DC - 1; j >= 0; --j) suf[j] = suf[j + 1] * tq[j];
                    bool zz = (pre[DC] == 0.0f);  // some t==0 zeroes the whole check
                    #pragma unroll
                    for (int j = 0; j < DC; ++j) {
                        float lo = pre[j] * suf[j + 1];
                        lo = fminf(fmaxf(lo, -CLIP_F), CLIP_F);
                        float q = (1.0f + lo) * __builtin_amdgcn_rcpf(1.0f - lo);
                        *(float*)(mb + ceb[k][j]) = zz ? 1.0f : q;
                    }
                }
            }
        }
        __syncthreads();

        // ---- variable phase: depth-2 pipelined contiguous load -> compute -> store ----
        const bool last = (iter == N_ITER - 1);
        {
            float qb[3][3];
            #pragma unroll
            for (int s = 0; s < VPT + 2; ++s) {
                if (s < VPT) {
                    int v = tid + s * NTHREADS;
                    qb[s % 3][0] = m[3 * v];
                    qb[s % 3][1] = m[3 * v + 1];
                    qb[s % 3][2] = m[3 * v + 2];
                }
                if (s >= 2) {
                    const int k = s - 2;
                    int v = tid + k * NTHREADS;
                    float q0 = qb[k % 3][0], q1 = qb[k % 3][1], q2 = qb[k % 3][2];
                    float q01 = q0 * q1, q12 = q1 * q2, q02 = q0 * q2;
                    // this iteration's marginal: llr + sum(ext) = llr + log(q0q1q2)
                    orow[(size_t)iter * (BATCH * N_VAR) + v] = l[k] + __logf(q01 * q2);
                    if (!last) {
                        float E0 = el[k] * q12, E1 = el[k] * q02, E2 = el[k] * q01;
                        m[3 * v]     = (E0 - 1.0f) * __builtin_amdgcn_rcpf(E0 + 1.0f);
                        m[3 * v + 1] = (E1 - 1.0f) * __builtin_amdgcn_rcpf(E1 + 1.0f);
                        m[3 * v + 2] = (E2 - 1.0f) * __builtin_amdgcn_rcpf(E2 + 1.0f);
                    }
                }
            }
        }
        if (!last) __syncthreads();
    }
}

extern "C" void kernel_launch(void* const* d_in, const int* in_sizes, int n_in,
                              void* d_out, int out_size, void* d_ws, size_t ws_size,
                              hipStream_t stream) {
    const float* llr       = (const float*)d_in[0];
    // d_in[1] = var_index: deterministic repeat(arange(N_VAR),3) — structure used directly
    const int*   chk_index = (const int*)d_in[2];
    float*       out       = (float*)d_out;

    int* cnt       = (int*)d_ws;
    int* chk_edges = cnt + N_CHK;

    hipMemsetAsync(cnt, 0, N_CHK * sizeof(int), stream);
    k_build<<<(N_EDGE + 255) / 256, 256, 0, stream>>>(chk_index, cnt, chk_edges);
    k_spa  <<<BATCH, 1024, 0, stream>>>(llr, chk_edges, out);
}